// Round 6
// baseline (679.058 us; speedup 1.0000x reference)
//
#include <hip/hip_runtime.h>
#include <hip/hip_cooperative_groups.h>

namespace cg = cooperative_groups;

#define S_SHIFT 8
#define S_NODES 256          // nodes per bucket (dst_local = dst & 255)
#define NBKT    400          // LDS array size (>= B = 391)
#define CAP     5120         // bucket capacity (mean ~4092, +25% slack)
#define CHUNK   4096         // edges per scatter task -> 391 scatter tasks
#define NREP    8            // LDS accumulator replicas: one per wave
#define TPB     512          // 8 waves
#define NDOT    633          // dots tasks (scatter 391 + dots 633 = 1024 tasks)
#define MAXGRID 1024         // 4 blocks/CU x 256 CUs
#define NCU     256

// 24 KB union -> 4 blocks/CU (LDS 96/160 KB, waves 32/32)
union __align__(16) SMem {
    struct { int hist[NBKT], lbase[NBKT], lcur[NBKT]; } sc;                     // scatter
    struct { float wv[192], uu[128], vl2[128], vr2[128], w2[32]; } fo;          // fold+dots
    struct { float aB[NREP][S_NODES], aC[NREP][S_NODES]; int cnt[NREP][S_NODES]; } a1; // aggA
    struct { float a2[NREP][S_NODES]; } ab;                                     // aggB
};

// Packed edge: (src << 8) | (dst & 255)   (src < 2^17 -> 25 bits)
__global__ __launch_bounds__(TPB, 8) void mega_kernel(
    const float* __restrict__ x,
    const int* __restrict__ src, const int* __restrict__ dst,
    int E, int N, int B, int nscat,
    int* __restrict__ cursor, unsigned* __restrict__ bucket,
    const float* __restrict__ Wl1, const float* __restrict__ Wr1, const float* __restrict__ b1,
    const float* __restrict__ Wl2, const float* __restrict__ Wr2, const float* __restrict__ b2,
    const float* __restrict__ Wfc1, const float* __restrict__ bfc1,
    const float* __restrict__ Wfc2, const float* __restrict__ bfc2,
    float* __restrict__ ga, float2* __restrict__ gbc, float* __restrict__ c01,
    float* __restrict__ q, float* __restrict__ inv,
    float* __restrict__ sB0, float* __restrict__ sC0, int* __restrict__ cnt0,
    float* __restrict__ sB1, float* __restrict__ sC1, int* __restrict__ cnt1,
    float* __restrict__ outp)
{
    __shared__ SMem sm;
    cg::grid_group grid = cg::this_grid();
    int t = threadIdx.x;
    int l = t & 63;          // lane
    int w = t >> 6;          // wave (0..7)
    int gsz = gridDim.x;

    // ================= P0: scatter tasks [0,nscat) | fold+dots tasks [nscat,nscat+NDOT) =================
    {
        int ntask0 = nscat + NDOT;
        bool folded = false;
        for (int task = blockIdx.x; task < ntask0; task += gsz) {
            if (task < nscat) {
                // ---- scatter (R0-proven inner loop) ----
                int e0 = task * CHUNK;
                int cnt = E - e0; if (cnt > CHUNK) cnt = CHUNK;
                for (int i = t; i < B; i += TPB) sm.sc.hist[i] = 0;
                __syncthreads();
                for (int i = t; i < cnt; i += TPB)
                    atomicAdd(&sm.sc.hist[dst[e0 + i] >> S_SHIFT], 1);
                __syncthreads();
                for (int i = t; i < B; i += TPB) {
                    sm.sc.lcur[i] = 0;
                    if (sm.sc.hist[i] > 0) sm.sc.lbase[i] = atomicAdd(&cursor[i], sm.sc.hist[i]);
                }
                __syncthreads();
                for (int i = t; i < cnt; i += TPB) {
                    int d = dst[e0 + i], s = src[e0 + i];   // L2-hot re-read
                    int bb = d >> S_SHIFT;
                    int off = atomicAdd(&sm.sc.lcur[bb], 1);
                    bucket[(size_t)bb * CAP + (unsigned)(sm.sc.lbase[bb] + off)] =
                        ((unsigned)s << S_SHIFT) | (unsigned)(d & (S_NODES - 1));
                }
                __syncthreads();
            } else {
                if (!folded) {
                    folded = true;
                    // ---- fold (8-wave, R0-proven) ----
                    if (t < 32) sm.fo.w2[t] = Wfc2[t];
                    __syncthreads();
                    for (int j = 0; j < 16; ++j) {   // uu = Wfc1 @ Wfc2
                        int i = w + 8 * j;
                        float p = (l < 32) ? Wfc1[i * 32 + l] * sm.fo.w2[l] : 0.f;
                        for (int m = 16; m; m >>= 1) p += __shfl_xor(p, m);
                        if (l == 0) sm.fo.uu[i] = p;
                    }
                    __syncthreads();
                    for (int j = 0; j < 16; ++j) {   // vl2 = Wl2 @ uu, vr2 = Wr2 @ uu
                        int i = w + 8 * j;
                        float ua = sm.fo.uu[l], ub = sm.fo.uu[64 + l];
                        float pa = Wl2[i * 128 + l] * ua + Wl2[i * 128 + 64 + l] * ub;
                        float pb = Wr2[i * 128 + l] * ua + Wr2[i * 128 + 64 + l] * ub;
                        for (int m = 32; m; m >>= 1) { pa += __shfl_xor(pa, m); pb += __shfl_xor(pb, m); }
                        if (l == 0) { sm.fo.vl2[i] = pa; sm.fo.vr2[i] = pb; }
                    }
                    __syncthreads();
                    for (int j = 0; j < 8; ++j) {    // wv = {w_a,w_b,w_c}
                        int i = w + 8 * j;
                        float l1a = Wl1[i * 128 + l], l1b = Wl1[i * 128 + 64 + l];
                        float r1a = Wr1[i * 128 + l], r1b = Wr1[i * 128 + 64 + l];
                        float La = sm.fo.vl2[l], Lb = sm.fo.vl2[64 + l];
                        float Ra = sm.fo.vr2[l], Rb = sm.fo.vr2[64 + l];
                        float pc = l1a * La + l1b * Lb;
                        float pb = l1a * Ra + l1b * Rb + r1a * La + r1b * Lb;
                        float pa = r1a * Ra + r1b * Rb;
                        for (int m = 32; m; m >>= 1) {
                            pa += __shfl_xor(pa, m); pb += __shfl_xor(pb, m); pc += __shfl_xor(pc, m);
                        }
                        if (l == 0) { sm.fo.wv[i] = pa; sm.fo.wv[64 + i] = pb; sm.fo.wv[128 + i] = pc; }
                    }
                    __syncthreads();
                }
                if (task == nscat && w == 7) {   // c0, c1 (one block publishes)
                    float p0 = b1[l] * sm.fo.vr2[l] + b1[64 + l] * sm.fo.vr2[64 + l]
                             + b2[l] * sm.fo.uu[l] + b2[64 + l] * sm.fo.uu[64 + l];
                    if (l < 32) p0 += bfc1[l] * sm.fo.w2[l];
                    float p1 = b1[l] * sm.fo.vl2[l] + b1[64 + l] * sm.fo.vl2[64 + l];
                    for (int m = 32; m; m >>= 1) { p0 += __shfl_xor(p0, m); p1 += __shfl_xor(p1, m); }
                    if (l == 0) { c01[0] = p0 + bfc2[0]; c01[1] = p1; }
                }
                // ---- dots: 4 nodes/wave, float4, 16 lanes per node ----
                int dtask = task - nscat;
                int fp = l & 15, sub = l >> 4;
                float4 wa4 = ((const float4*)sm.fo.wv)[fp];
                float4 wb4 = ((const float4*)sm.fo.wv)[16 + fp];
                float4 wc4 = ((const float4*)sm.fo.wv)[32 + fp];
                const float4* x4 = (const float4*)x;
                int Q = (N + 3) >> 2;
                for (int qd = dtask * 8 + w; qd < Q; qd += NDOT * 8) {
                    int node = qd * 4 + sub;
                    float a = 0.f, b = 0.f, c = 0.f;
                    if (node < N) {
                        float4 v = x4[(size_t)node * 16 + fp];
                        a = v.x * wa4.x + v.y * wa4.y + v.z * wa4.z + v.w * wa4.w;
                        b = v.x * wb4.x + v.y * wb4.y + v.z * wb4.z + v.w * wb4.w;
                        c = v.x * wc4.x + v.y * wc4.y + v.z * wc4.z + v.w * wc4.w;
                    }
                    for (int m = 8; m; m >>= 1) {
                        a += __shfl_xor(a, m); b += __shfl_xor(b, m); c += __shfl_xor(c, m);
                    }
                    if (fp == 0 && node < N) { ga[node] = a; gbc[node] = make_float2(b, c); }
                }
            }
        }
    }
    __threadfence();
    grid.sync();

    // ================= P1: aggA — two half-bucket tasks per bucket, plain-store partials =================
    {
        int ntA = 2 * B;
        for (int tid = blockIdx.x; tid < ntA; tid += gsz) {
            int b = tid >> 1, hi = tid & 1;
            int r = t >> 6;
            float* aBf = (float*)sm.a1.aB; float* aCf = (float*)sm.a1.aC; int* cnf = (int*)sm.a1.cnt;
            for (int i = t; i < NREP * S_NODES; i += TPB) { aBf[i] = 0.f; aCf[i] = 0.f; cnf[i] = 0; }
            __syncthreads();
            int n = cursor[b];
            int half = (((n + 1) >> 1) + 3) & ~3;            // 4-aligned split point
            if (half > n) half = n;
            int start = hi ? half : 0;
            int end   = hi ? n    : half;
            const unsigned* bp = bucket + (size_t)b * CAP;
            int m = end - start;
            int m4 = m & ~3;
            for (int i = start + 4 * t; i < start + m4; i += 4 * TPB) {
                uint4 e4 = *(const uint4*)(bp + i);
                float2 g0 = gbc[e4.x >> S_SHIFT];
                float2 g1 = gbc[e4.y >> S_SHIFT];
                float2 g2 = gbc[e4.z >> S_SHIFT];
                float2 g3 = gbc[e4.w >> S_SHIFT];
                int d0 = e4.x & (S_NODES - 1), d1 = e4.y & (S_NODES - 1);
                int d2 = e4.z & (S_NODES - 1), d3 = e4.w & (S_NODES - 1);
                atomicAdd(&sm.a1.aB[r][d0], g0.x); atomicAdd(&sm.a1.aC[r][d0], g0.y); atomicAdd(&sm.a1.cnt[r][d0], 1);
                atomicAdd(&sm.a1.aB[r][d1], g1.x); atomicAdd(&sm.a1.aC[r][d1], g1.y); atomicAdd(&sm.a1.cnt[r][d1], 1);
                atomicAdd(&sm.a1.aB[r][d2], g2.x); atomicAdd(&sm.a1.aC[r][d2], g2.y); atomicAdd(&sm.a1.cnt[r][d2], 1);
                atomicAdd(&sm.a1.aB[r][d3], g3.x); atomicAdd(&sm.a1.aC[r][d3], g3.y); atomicAdd(&sm.a1.cnt[r][d3], 1);
            }
            int it = start + m4 + t;
            if (it < end) {
                unsigned uu = bp[it];
                float2 g = gbc[uu >> S_SHIFT];
                int dl = uu & (S_NODES - 1);
                atomicAdd(&sm.a1.aB[r][dl], g.x); atomicAdd(&sm.a1.aC[r][dl], g.y); atomicAdd(&sm.a1.cnt[r][dl], 1);
            }
            __syncthreads();
            if (t < S_NODES) {
                int node = (b << S_SHIFT) + t;
                if (node < N) {
                    float sb = 0.f, sc = 0.f; int d = 0;
                    #pragma unroll
                    for (int k = 0; k < NREP; ++k) { sb += sm.a1.aB[k][t]; sc += sm.a1.aC[k][t]; d += sm.a1.cnt[k][t]; }
                    if (hi == 0) { sB0[node] = sb; sC0[node] = sc; cnt0[node] = d; }
                    else         { sB1[node] = sb; sC1[node] = sc; cnt1[node] = d; }
                }
            }
            __syncthreads();
        }
    }
    __threadfence();
    grid.sync();

    // ================= P2: finalize — combine halves -> q, inv, out=t1 (coalesced) =================
    {
        float c0 = c01[0], c1 = c01[1];
        for (int node = blockIdx.x * TPB + t; node < N; node += gsz * TPB) {
            int d = cnt0[node] + cnt1[node];
            float sb = sB0[node] + sB1[node];
            float sc = sC0[node] + sC1[node];
            float iv = 1.0f / ((d > 0) ? (float)d : 1.0f);
            q[node]    = iv * sc;
            inv[node]  = iv;
            outp[node] = ga[node] + iv * sb + c0 + (d > 0 ? c1 : 0.f);
        }
    }
    __threadfence();
    grid.sync();

    // ================= P3: aggB — two half-bucket tasks per bucket; coalesced atomics on out =================
    {
        int ntA = 2 * B;
        for (int tid = blockIdx.x; tid < ntA; tid += gsz) {
            int b = tid >> 1, hi = tid & 1;
            int r = t >> 6;
            float* a2f = (float*)sm.ab.a2;
            for (int i = t; i < NREP * S_NODES; i += TPB) a2f[i] = 0.f;
            __syncthreads();
            int n = cursor[b];
            int half = (((n + 1) >> 1) + 3) & ~3;
            if (half > n) half = n;
            int start = hi ? half : 0;
            int end   = hi ? n    : half;
            const unsigned* bp = bucket + (size_t)b * CAP;
            int m = end - start;
            int m4 = m & ~3;
            for (int i = start + 4 * t; i < start + m4; i += 4 * TPB) {
                uint4 e4 = *(const uint4*)(bp + i);
                float q0 = q[e4.x >> S_SHIFT], q1 = q[e4.y >> S_SHIFT];
                float q2 = q[e4.z >> S_SHIFT], q3 = q[e4.w >> S_SHIFT];
                atomicAdd(&sm.ab.a2[r][e4.x & (S_NODES - 1)], q0);
                atomicAdd(&sm.ab.a2[r][e4.y & (S_NODES - 1)], q1);
                atomicAdd(&sm.ab.a2[r][e4.z & (S_NODES - 1)], q2);
                atomicAdd(&sm.ab.a2[r][e4.w & (S_NODES - 1)], q3);
            }
            int it = start + m4 + t;
            if (it < end) {
                unsigned uu = bp[it];
                atomicAdd(&sm.ab.a2[r][uu & (S_NODES - 1)], q[uu >> S_SHIFT]);
            }
            __syncthreads();
            if (t < S_NODES) {
                int node = (b << S_SHIFT) + t;
                if (node < N) {
                    float s2 = 0.f;
                    #pragma unroll
                    for (int k = 0; k < NREP; ++k) s2 += sm.ab.a2[k][t];
                    atomicAdd(&outp[node], inv[node] * s2);   // contiguous -> cheap
                }
            }
            __syncthreads();
        }
    }
}

extern "C" void kernel_launch(void* const* d_in, const int* in_sizes, int n_in,
                              void* d_out, int out_size, void* d_ws, size_t ws_size,
                              hipStream_t stream) {
    const float* x    = (const float*)d_in[0];
    const int*   eidx = (const int*)d_in[1];   // [2, E]
    // d_in[2] = edge_weight: unused by the reference
    const float* Wl1  = (const float*)d_in[3];
    const float* Wr1  = (const float*)d_in[4];
    const float* b1   = (const float*)d_in[5];
    const float* Wl2  = (const float*)d_in[6];
    const float* Wr2  = (const float*)d_in[7];
    const float* b2   = (const float*)d_in[8];
    const float* Wfc1 = (const float*)d_in[9];
    const float* bfc1 = (const float*)d_in[10];
    const float* Wfc2 = (const float*)d_in[11];
    const float* bfc2 = (const float*)d_in[12];

    const int N = in_sizes[0] / 64;
    const int E = in_sizes[2];
    const int* src = eidx;
    const int* dst = eidx + E;
    const int B = (N + S_NODES - 1) >> S_SHIFT;      // 391 buckets
    const int nscat = (E + CHUNK - 1) / CHUNK;       // 391 scatter tasks

    char* ws = (char*)d_ws;
    size_t o = 0;
    auto take = [&](size_t bytes) { char* p = ws + o; o += (bytes + 127) & ~(size_t)127; return p; };
    int*      cursor = (int*)take(NBKT * 4);          // only this needs zeroing
    float*    c01    = (float*)take(64);
    float*    ga     = (float*)take((size_t)N * 4);
    float*    q      = (float*)take((size_t)N * 4);
    float*    inv    = (float*)take((size_t)N * 4);
    float*    sB0    = (float*)take((size_t)N * 4);
    float*    sC0    = (float*)take((size_t)N * 4);
    int*      cnt0   = (int*)take((size_t)N * 4);
    float*    sB1    = (float*)take((size_t)N * 4);
    float*    sC1    = (float*)take((size_t)N * 4);
    int*      cnt1   = (int*)take((size_t)N * 4);
    float2*   gbc    = (float2*)take((size_t)N * 8);
    unsigned* bucket = (unsigned*)take((size_t)B * CAP * 4);

    hipMemsetAsync(cursor, 0, NBKT * 4, stream);

    // Cooperative grid: clamp to guaranteed-resident block count (expect 4/CU -> 1024).
    int maxb = 0;
    if (hipOccupancyMaxActiveBlocksPerMultiprocessor(&maxb, mega_kernel, TPB, 0) != hipSuccess || maxb < 1)
        maxb = 1;
    int gridn = maxb * NCU; if (gridn > MAXGRID) gridn = MAXGRID;

    int E_ = E, N_ = N, B_ = B, nscat_ = nscat;
    void* args[] = {
        (void*)&x, (void*)&src, (void*)&dst, (void*)&E_, (void*)&N_, (void*)&B_, (void*)&nscat_,
        (void*)&cursor, (void*)&bucket,
        (void*)&Wl1, (void*)&Wr1, (void*)&b1, (void*)&Wl2, (void*)&Wr2, (void*)&b2,
        (void*)&Wfc1, (void*)&bfc1, (void*)&Wfc2, (void*)&bfc2,
        (void*)&ga, (void*)&gbc, (void*)&c01, (void*)&q, (void*)&inv,
        (void*)&sB0, (void*)&sC0, (void*)&cnt0, (void*)&sB1, (void*)&sC1, (void*)&cnt1,
        (void*)&d_out
    };
    hipLaunchCooperativeKernel(reinterpret_cast<void*>(mega_kernel),
                               dim3(gridn), dim3(TPB), args, 0, stream);
}

// Round 7
// 181.770 us; speedup vs baseline: 3.7358x; 3.7358x over previous
//
#include <hip/hip_runtime.h>

#define S_SHIFT 8
#define S_NODES 256          // nodes per bucket (dst_local = dst & 255)
#define NBKT    400          // LDS array size (>= B = 391)
#define CAP     5120         // bucket capacity (mean ~4092, +25% slack)
#define CHUNK   4096         // edges per scatter block -> 391 scatter blocks, 24 edge-ops/thread
#define NREP    8            // LDS accumulator replicas: one per wave (512 thr)
#define FTH     512          // fused kernel block size
#define NDOTS   633          // dots-role blocks (391 + 633 = 1024 = 4 blocks/CU)

// Fused: scatter role (blocks [0,nscat)) + fold/dots role (blocks [nscat,nscat+NDOTS)).
// Packed edge: (src << 8) | (dst & 255)   (src < 2^17 -> 25 bits)
__global__ __launch_bounds__(FTH) void fused_kernel(
    const float* __restrict__ x,
    const int* __restrict__ src, const int* __restrict__ dst,
    int E, int N, int B, int nscat,
    int* __restrict__ cursor, unsigned* __restrict__ bucket,
    const float* __restrict__ Wl1, const float* __restrict__ Wr1, const float* __restrict__ b1,
    const float* __restrict__ Wl2, const float* __restrict__ Wr2, const float* __restrict__ b2,
    const float* __restrict__ Wfc1, const float* __restrict__ bfc1,
    const float* __restrict__ Wfc2, const float* __restrict__ bfc2,
    float* __restrict__ ga, float2* __restrict__ gbc, float* __restrict__ c01)
{
    __shared__ int hist[NBKT], lbase[NBKT], lcur[NBKT];          // scatter role
    __shared__ __align__(16) float wv[192];                      // dots role
    __shared__ float uu[128], vl2[128], vr2[128], w2[32];
    int t = threadIdx.x;
    int l = t & 63;          // lane
    int w = t >> 6;          // wave (0..7)

    if ((int)blockIdx.x < nscat) {
        // ---------------- scatter role (R0-proven inner loops, half chunk) ----------------
        int e0 = blockIdx.x * CHUNK;
        int cnt = E - e0; if (cnt > CHUNK) cnt = CHUNK;
        for (int i = t; i < B; i += FTH) hist[i] = 0;
        __syncthreads();
        for (int i = t; i < cnt; i += FTH)
            atomicAdd(&hist[dst[e0 + i] >> S_SHIFT], 1);
        __syncthreads();
        for (int i = t; i < B; i += FTH) {
            lcur[i] = 0;
            if (hist[i] > 0) lbase[i] = atomicAdd(&cursor[i], hist[i]);
        }
        __syncthreads();
        for (int i = t; i < cnt; i += FTH) {
            int d = dst[e0 + i], s = src[e0 + i];   // L2-hot re-read
            int bb = d >> S_SHIFT;
            int off = atomicAdd(&lcur[bb], 1);
            bucket[(size_t)bb * CAP + (unsigned)(lbase[bb] + off)] =
                ((unsigned)s << S_SHIFT) | (unsigned)(d & (S_NODES - 1));
        }
    } else {
        // ---------------- fold role (8-wave, redundant per block, hidden under scatter) ----------------
        if (t < 32) w2[t] = Wfc2[t];
        __syncthreads();
        for (int j = 0; j < 16; ++j) {   // uu = Wfc1 @ Wfc2  (Wfc1 [128,32] row-major)
            int i = w + 8 * j;
            float p = (l < 32) ? Wfc1[i * 32 + l] * w2[l] : 0.f;
            for (int m = 16; m; m >>= 1) p += __shfl_xor(p, m);
            if (l == 0) uu[i] = p;
        }
        __syncthreads();
        for (int j = 0; j < 16; ++j) {   // vl2 = Wl2 @ uu, vr2 = Wr2 @ uu ([128,128] row-major)
            int i = w + 8 * j;
            float ua = uu[l], ub = uu[64 + l];
            float pa = Wl2[i * 128 + l] * ua + Wl2[i * 128 + 64 + l] * ub;
            float pb = Wr2[i * 128 + l] * ua + Wr2[i * 128 + 64 + l] * ub;
            for (int m = 32; m; m >>= 1) { pa += __shfl_xor(pa, m); pb += __shfl_xor(pb, m); }
            if (l == 0) { vl2[i] = pa; vr2[i] = pb; }
        }
        __syncthreads();
        for (int j = 0; j < 8; ++j) {    // wv = {w_a,w_b,w_c}  (Wl1/Wr1 [64,128] row-major)
            int i = w + 8 * j;
            float l1a = Wl1[i * 128 + l], l1b = Wl1[i * 128 + 64 + l];
            float r1a = Wr1[i * 128 + l], r1b = Wr1[i * 128 + 64 + l];
            float La = vl2[l], Lb = vl2[64 + l], Ra = vr2[l], Rb = vr2[64 + l];
            float pc = l1a * La + l1b * Lb;
            float pb = l1a * Ra + l1b * Rb + r1a * La + r1b * Lb;
            float pa = r1a * Ra + r1b * Rb;
            for (int m = 32; m; m >>= 1) {
                pa += __shfl_xor(pa, m); pb += __shfl_xor(pb, m); pc += __shfl_xor(pc, m);
            }
            if (l == 0) { wv[i] = pa; wv[64 + i] = pb; wv[128 + i] = pc; }
        }
        if ((int)blockIdx.x == nscat && w == 7) {   // c0, c1 (one block publishes)
            float p0 = b1[l] * vr2[l] + b1[64 + l] * vr2[64 + l]
                     + b2[l] * uu[l] + b2[64 + l] * uu[64 + l];
            if (l < 32) p0 += bfc1[l] * w2[l];
            float p1 = b1[l] * vl2[l] + b1[64 + l] * vl2[64 + l];
            for (int m = 32; m; m >>= 1) { p0 += __shfl_xor(p0, m); p1 += __shfl_xor(p1, m); }
            if (l == 0) { c01[0] = p0 + bfc2[0]; c01[1] = p1; }
        }
        __syncthreads();

        // ---------------- dots: 4 nodes/wave, float4, 16 lanes per node ----------------
        int fp = l & 15, sub = l >> 4;
        float4 wa4 = ((const float4*)wv)[fp];
        float4 wb4 = ((const float4*)wv)[16 + fp];
        float4 wc4 = ((const float4*)wv)[32 + fp];
        const float4* x4 = (const float4*)x;
        int Q = (N + 3) >> 2;
        for (int qd = ((int)blockIdx.x - nscat) * 8 + w; qd < Q; qd += NDOTS * 8) {
            int node = qd * 4 + sub;
            float a = 0.f, b = 0.f, c = 0.f;
            if (node < N) {
                float4 v = x4[(size_t)node * 16 + fp];
                a = v.x * wa4.x + v.y * wa4.y + v.z * wa4.z + v.w * wa4.w;
                b = v.x * wb4.x + v.y * wb4.y + v.z * wb4.z + v.w * wb4.w;
                c = v.x * wc4.x + v.y * wc4.y + v.z * wc4.z + v.w * wc4.w;
            }
            for (int m = 8; m; m >>= 1) {
                a += __shfl_xor(a, m); b += __shfl_xor(b, m); c += __shfl_xor(c, m);
            }
            if (fp == 0 && node < N) { ga[node] = a; gbc[node] = make_float2(b, c); }
        }
    }
}

// One block per bucket, 512 threads, per-wave (8x) replicated LDS accumulators.
// (R0-proven kernel, unchanged.)
__global__ __launch_bounds__(512) void aggA_kernel(
    const unsigned* __restrict__ bucket, const int* __restrict__ cursor,
    const float2* __restrict__ gbc, const float* __restrict__ ga,
    const float* __restrict__ c01,
    float* __restrict__ q, float* __restrict__ t1, float* __restrict__ inv, int N)
{
    __shared__ float aB[NREP][S_NODES], aC[NREP][S_NODES];
    __shared__ int cnt[NREP][S_NODES];
    int t = threadIdx.x, b = blockIdx.x;
    int r = t >> 6;                       // private replica per wave
    float* aBf = (float*)aB; float* aCf = (float*)aC; int* cnf = (int*)cnt;
    for (int i = t; i < NREP * S_NODES; i += 512) { aBf[i] = 0.f; aCf[i] = 0.f; cnf[i] = 0; }
    __syncthreads();
    int n = cursor[b];
    const unsigned* bp = bucket + (size_t)b * CAP;
    int n4 = n & ~3;
    for (int i = 4 * t; i < n4; i += 4 * 512) {
        uint4 e4 = *(const uint4*)(bp + i);
        float2 g0 = gbc[e4.x >> S_SHIFT];
        float2 g1 = gbc[e4.y >> S_SHIFT];
        float2 g2 = gbc[e4.z >> S_SHIFT];
        float2 g3 = gbc[e4.w >> S_SHIFT];
        int d0 = e4.x & (S_NODES - 1), d1 = e4.y & (S_NODES - 1);
        int d2 = e4.z & (S_NODES - 1), d3 = e4.w & (S_NODES - 1);
        atomicAdd(&aB[r][d0], g0.x); atomicAdd(&aC[r][d0], g0.y); atomicAdd(&cnt[r][d0], 1);
        atomicAdd(&aB[r][d1], g1.x); atomicAdd(&aC[r][d1], g1.y); atomicAdd(&cnt[r][d1], 1);
        atomicAdd(&aB[r][d2], g2.x); atomicAdd(&aC[r][d2], g2.y); atomicAdd(&cnt[r][d2], 1);
        atomicAdd(&aB[r][d3], g3.x); atomicAdd(&aC[r][d3], g3.y); atomicAdd(&cnt[r][d3], 1);
    }
    if (n4 + t < n) {
        unsigned uu = bp[n4 + t];
        float2 g = gbc[uu >> S_SHIFT];
        int dl = uu & (S_NODES - 1);
        atomicAdd(&aB[r][dl], g.x); atomicAdd(&aC[r][dl], g.y); atomicAdd(&cnt[r][dl], 1);
    }
    __syncthreads();
    if (t < S_NODES) {
        int node = (b << S_SHIFT) + t;
        if (node < N) {
            float sb = 0.f, sc = 0.f; int d = 0;
            #pragma unroll
            for (int k = 0; k < NREP; ++k) { sb += aB[k][t]; sc += aC[k][t]; d += cnt[k][t]; }
            float iv = 1.0f / ((d > 0) ? (float)d : 1.0f);
            inv[node] = iv;
            q[node]   = iv * sc;
            t1[node]  = ga[node] + iv * sb + c01[0] + (d > 0 ? c01[1] : 0.f);
        }
    }
}

__global__ __launch_bounds__(512) void aggB_kernel(
    const unsigned* __restrict__ bucket, const int* __restrict__ cursor,
    const float* __restrict__ q, const float* __restrict__ t1,
    const float* __restrict__ inv, float* __restrict__ out, int N)
{
    __shared__ float a2[NREP][S_NODES];
    int t = threadIdx.x, b = blockIdx.x;
    int r = t >> 6;
    float* a2f = (float*)a2;
    for (int i = t; i < NREP * S_NODES; i += 512) a2f[i] = 0.f;
    __syncthreads();
    int n = cursor[b];
    const unsigned* bp = bucket + (size_t)b * CAP;
    int n4 = n & ~3;
    for (int i = 4 * t; i < n4; i += 4 * 512) {
        uint4 e4 = *(const uint4*)(bp + i);
        float q0 = q[e4.x >> S_SHIFT], q1 = q[e4.y >> S_SHIFT];
        float q2 = q[e4.z >> S_SHIFT], q3 = q[e4.w >> S_SHIFT];
        atomicAdd(&a2[r][e4.x & (S_NODES - 1)], q0);
        atomicAdd(&a2[r][e4.y & (S_NODES - 1)], q1);
        atomicAdd(&a2[r][e4.z & (S_NODES - 1)], q2);
        atomicAdd(&a2[r][e4.w & (S_NODES - 1)], q3);
    }
    if (n4 + t < n) {
        unsigned uu = bp[n4 + t];
        atomicAdd(&a2[r][uu & (S_NODES - 1)], q[uu >> S_SHIFT]);
    }
    __syncthreads();
    if (t < S_NODES) {
        int node = (b << S_SHIFT) + t;
        if (node < N) {
            float s2 = 0.f;
            #pragma unroll
            for (int k = 0; k < NREP; ++k) s2 += a2[k][t];
            out[node] = t1[node] + inv[node] * s2;
        }
    }
}

extern "C" void kernel_launch(void* const* d_in, const int* in_sizes, int n_in,
                              void* d_out, int out_size, void* d_ws, size_t ws_size,
                              hipStream_t stream) {
    const float* x    = (const float*)d_in[0];
    const int*   eidx = (const int*)d_in[1];   // [2, E]
    // d_in[2] = edge_weight: unused by the reference
    const float* Wl1  = (const float*)d_in[3];
    const float* Wr1  = (const float*)d_in[4];
    const float* b1   = (const float*)d_in[5];
    const float* Wl2  = (const float*)d_in[6];
    const float* Wr2  = (const float*)d_in[7];
    const float* b2   = (const float*)d_in[8];
    const float* Wfc1 = (const float*)d_in[9];
    const float* bfc1 = (const float*)d_in[10];
    const float* Wfc2 = (const float*)d_in[11];
    const float* bfc2 = (const float*)d_in[12];

    const int N = in_sizes[0] / 64;
    const int E = in_sizes[2];
    const int* src = eidx;
    const int* dst = eidx + E;
    const int B = (N + S_NODES - 1) >> S_SHIFT;      // 391 buckets (<= NBKT)
    const int nscat = (E + CHUNK - 1) / CHUNK;       // 391 scatter blocks

    // workspace: [cursor 2KB][c01 2KB][ga 4N][q 4N][t1 4N][inv 4N][gbc 8N][bucket B*CAP*4]
    char* ws = (char*)d_ws;
    int*      cursor = (int*)(ws);
    float*    c01    = (float*)(ws + 2048);
    float*    ga     = (float*)(ws + 4096);
    float*    q      = (float*)(ws + 4096 + (size_t)N * 4);
    float*    t1     = (float*)(ws + 4096 + (size_t)N * 8);
    float*    inv    = (float*)(ws + 4096 + (size_t)N * 12);
    float2*   gbc    = (float2*)(ws + 4096 + (size_t)N * 16);
    unsigned* bucket = (unsigned*)(ws + 4096 + (size_t)N * 24);

    hipMemsetAsync(cursor, 0, 2048, stream);

    fused_kernel<<<nscat + NDOTS, FTH, 0, stream>>>(
        x, src, dst, E, N, B, nscat, cursor, bucket,
        Wl1, Wr1, b1, Wl2, Wr2, b2, Wfc1, bfc1, Wfc2, bfc2,
        ga, gbc, c01);

    aggA_kernel<<<B, 512, 0, stream>>>(bucket, cursor, gbc, ga, c01, q, t1, inv, N);
    aggB_kernel<<<B, 512, 0, stream>>>(bucket, cursor, q, t1, inv, (float*)d_out, N);
}